// Round 4
// baseline (2768.546 us; speedup 1.0000x reference)
//
#include <hip/hip_runtime.h>

#define BB 128
#define TT 2048
#define II 64
#define HH 128
#define KK 192  // I + H (concatenated dot length)
#define KC 48   // K-chunk per lane (KK/4)
#define NB 2    // batches per block

typedef _Float16 h2 __attribute__((ext_vector_type(2)));

__device__ __forceinline__ h2 mkh2(float a, float b) {
    h2 r; r.x = (_Float16)a; r.y = (_Float16)b; return r;
}

__device__ __forceinline__ h2 u2h(unsigned u) {
    return __builtin_bit_cast(h2, u);
}

__device__ __forceinline__ float fdot2f(h2 a, h2 b, float c) {
#if __has_builtin(__builtin_amdgcn_fdot2)
    return __builtin_amdgcn_fdot2(a, b, c, false);
#else
    return fmaf((float)a.y, (float)b.y, fmaf((float)a.x, (float)b.x, c));
#endif
}

__device__ __forceinline__ float rcp_fast(float x) {
    return __builtin_amdgcn_rcpf(x);
}

__device__ __forceinline__ float tanh_fast(float x) {
    return fmaf(rcp_fast(1.0f + __expf(-2.0f * x)), 2.0f, -1.0f);
}

__device__ __forceinline__ float sigmoid_fast(float x) {
    return rcp_fast(1.0f + __expf(-x));
}

// DPP quad_perm cross-lane (within groups of 4 lanes), pure VALU — no LDS.
template <int CTRL>
__device__ __forceinline__ float dppq(float x) {
#if __has_builtin(__builtin_amdgcn_update_dpp)
    int i = __builtin_bit_cast(int, x);
    int r = __builtin_amdgcn_update_dpp(i, i, CTRL, 0xF, 0xF, true);
    return __builtin_bit_cast(float, r);
#else
    return __shfl_xor(x, (CTRL == 177) ? 1 : (CTRL == 78) ? 2 : 3, 4);
#endif
}

// One workgroup per TWO batch elements; 512 threads, grid = 64 blocks.
// Quad (lanes 4q..4q+3) owns h-element j. Lane kc = lane&3 computes partial
// dots of all four gate rows over K-chunk [48*kc, 48*kc+48) of [x | h], for
// BOTH batches, sharing one set of weight registers. The two batches'
// independent dot/act chains fill each other's latency; one barrier, one
// LDS-latency head, one act tail serve two recurrences.
__global__ __launch_bounds__(512, 2) void lstm_fused_kernel(
    const float* __restrict__ input,  // [B,T,I]
    const float* __restrict__ h0,     // [B,H]
    const float* __restrict__ c0,     // [B,H]
    const float* __restrict__ W_ih,   // [4H,I]
    const float* __restrict__ W_hh,   // [4H,H]
    const float* __restrict__ b_ih,   // [4H]
    const float* __restrict__ b_hh,   // [4H]
    float* __restrict__ out)          // [B*H] h_last, then [B,T,H] encoded
{
    // [buf][batch][h2 idx]: idx [0,32) = x_t (64 halfs), [32,96) = h (128).
    __shared__ __align__(16) h2 s_xh[2][NB][KK / 2];

    const int tid  = threadIdx.x;
    const int b0   = blockIdx.x * NB;
    const int lane = tid & 63;
    const int w    = tid >> 6;
    const int kc   = lane & 3;                  // K-chunk 0..3
    const int j    = (w << 4) | (lane >> 2);    // h element [0,128)

    // ---- weight chunks into registers (shared across both batches) ----
    h2 wreg[4][KC / 2];   // 96 h2 regs
    float bias[4];
#pragma unroll
    for (int g = 0; g < 4; ++g) {
        const int row = (g << 7) | j;
        bias[g] = b_ih[row] + b_hh[row];
        const float2* wi = reinterpret_cast<const float2*>(W_ih + row * II);
        const float2* wh = reinterpret_cast<const float2*>(W_hh + row * HH);
#pragma unroll
        for (int m = 0; m < KC / 2; ++m) {
            const int k = KC * kc + 2 * m;      // even; never straddles II
            float2 v = (k < II) ? wi[k >> 1] : wh[(k - II) >> 1];
            wreg[g][m] = mkh2(v.x, v.y);
        }
    }

    // ---- state init ----
    float cc0 = c0[(size_t)(b0 + 0) * HH + j];   // redundant per quad
    float cc1 = c0[(size_t)(b0 + 1) * HH + j];
    if (tid < 128) {
        // FULL h coverage: 64 float2 (=128 floats) per batch.
        const int bb = tid >> 6, i = tid & 63;
        float2 hv = reinterpret_cast<const float2*>(h0 + (size_t)(b0 + bb) * HH)[i];
        s_xh[0][bb][32 + i] = mkh2(hv.x, hv.y);
    }

    // ---- x prefetch: threads 0..63 hold 4 future float2 of x ----
    const int bbx = (tid >> 5) & 1, ix = tid & 31;
    const float2* xin = reinterpret_cast<const float2*>(input)
                        + (size_t)(b0 + bbx) * TT * 32 + ix;
    float2 xb0, xb1, xb2, xb3;
    if (tid < 64) {
        xb0 = xin[(size_t)0 * 32];
        xb1 = xin[(size_t)1 * 32];
        xb2 = xin[(size_t)2 * 32];
        xb3 = xin[(size_t)3 * 32];
        s_xh[0][bbx][ix] = mkh2(xb0.x, xb0.y);   // stage x for step 0
        xb0 = xin[(size_t)4 * 32];               // xb0 now holds x_4
    }
    __syncthreads();

    float* out_h = out;            // [B*H]
    float* out_e = out + BB * HH;  // [B*T*H]
    float hlast0 = 0.0f, hlast1 = 0.0f;

    auto step = [&](int t, float2& xbn) {
        const int cb = t & 1, nb = cb ^ 1;

        if (tid < 64) {
            s_xh[nb][bbx][ix] = mkh2(xbn.x, xbn.y);
            int tn = t + 5; if (tn > TT - 1) tn = TT - 1;   // clamped, harmless
            xbn = xin[(size_t)tn * 32];
        }

        const uint4* p0 = reinterpret_cast<const uint4*>(
            reinterpret_cast<const char*>(s_xh[cb][0]) + kc * (KC * 2));
        const uint4* p1 = reinterpret_cast<const uint4*>(
            reinterpret_cast<const char*>(s_xh[cb][1]) + kc * (KC * 2));

        float a0[4] = {0.f, 0.f, 0.f, 0.f};   // batch 0 partials
        float a1[4] = {0.f, 0.f, 0.f, 0.f};   // batch 1 partials
#pragma unroll
        for (int q = 0; q < 6; ++q) {
            uint4 v0 = p0[q];
            uint4 v1 = p1[q];
#pragma unroll
            for (int g = 0; g < 4; ++g) {
                a0[g] = fdot2f(wreg[g][4 * q + 0], u2h(v0.x), a0[g]);
                a1[g] = fdot2f(wreg[g][4 * q + 0], u2h(v1.x), a1[g]);
                a0[g] = fdot2f(wreg[g][4 * q + 1], u2h(v0.y), a0[g]);
                a1[g] = fdot2f(wreg[g][4 * q + 1], u2h(v1.y), a1[g]);
                a0[g] = fdot2f(wreg[g][4 * q + 2], u2h(v0.z), a0[g]);
                a1[g] = fdot2f(wreg[g][4 * q + 2], u2h(v1.z), a1[g]);
                a0[g] = fdot2f(wreg[g][4 * q + 3], u2h(v0.w), a0[g]);
                a1[g] = fdot2f(wreg[g][4 * q + 3], u2h(v1.w), a1[g]);
            }
        }

        // 2-round quad butterfly per batch: every lane gets all 4 gate sums.
        float u0[4], u1[4];
#pragma unroll
        for (int g = 0; g < 4; ++g) {
            float t0 = a0[g] + dppq<177>(a0[g]);
            float t1 = a1[g] + dppq<177>(a1[g]);
            u0[g] = t0 + dppq<78>(t0);
            u1[g] = t1 + dppq<78>(t1);
        }

        // activations (two independent chains — ILP)
        float i0 = sigmoid_fast(u0[0] + bias[0]);
        float i1 = sigmoid_fast(u1[0] + bias[0]);
        float f0 = sigmoid_fast(u0[1] + bias[1]);
        float f1 = sigmoid_fast(u1[1] + bias[1]);
        float g0 = tanh_fast(u0[2] + bias[2]);
        float g1 = tanh_fast(u1[2] + bias[2]);
        float o0 = sigmoid_fast(u0[3] + bias[3]);
        float o1 = sigmoid_fast(u1[3] + bias[3]);

        cc0 = fmaf(f0, cc0, i0 * g0);
        cc1 = fmaf(f1, cc1, i1 * g1);
        float hv0 = o0 * tanh_fast(cc0);
        float hv1 = o1 * tanh_fast(cc1);
        hlast0 = hv0;
        hlast1 = hv1;

        if (kc == 0) reinterpret_cast<_Float16*>(s_xh[nb][0])[II + j] = (_Float16)hv0;
        if (kc == 1) reinterpret_cast<_Float16*>(s_xh[nb][1])[II + j] = (_Float16)hv1;
        if (kc == 2) out_e[((size_t)(b0 + 0) * TT + t) * HH + j] = hv0;
        if (kc == 3) out_e[((size_t)(b0 + 1) * TT + t) * HH + j] = hv1;

        __syncthreads();
    };

    for (int t0 = 0; t0 < TT; t0 += 4) {
        step(t0 + 0, xb1);
        step(t0 + 1, xb2);
        step(t0 + 2, xb3);
        step(t0 + 3, xb0);
    }

    if (kc == 0) out_h[(size_t)(b0 + 0) * HH + j] = hlast0;
    if (kc == 1) out_h[(size_t)(b0 + 1) * HH + j] = hlast1;
}

extern "C" void kernel_launch(void* const* d_in, const int* in_sizes, int n_in,
                              void* d_out, int out_size, void* d_ws, size_t ws_size,
                              hipStream_t stream) {
    const float* input = (const float*)d_in[0];
    const float* h0    = (const float*)d_in[1];
    const float* c0    = (const float*)d_in[2];
    const float* W_ih  = (const float*)d_in[3];
    const float* W_hh  = (const float*)d_in[4];
    const float* b_ih  = (const float*)d_in[5];
    const float* b_hh  = (const float*)d_in[6];
    float* out = (float*)d_out;

    hipLaunchKernelGGL(lstm_fused_kernel, dim3(BB / NB), dim3(512), 0, stream,
                       input, h0, c0, W_ih, W_hh, b_ih, b_hh, out);
}

// Round 5
// 1292.802 us; speedup vs baseline: 2.1415x; 2.1415x over previous
//
#include <hip/hip_runtime.h>

#define BB 128
#define TT 2048
#define II 64
#define HH 128
#define KK 192  // I + H

typedef _Float16 h2 __attribute__((ext_vector_type(2)));
typedef _Float16 f16x8 __attribute__((ext_vector_type(8)));
typedef float f32x4 __attribute__((ext_vector_type(4)));

__device__ __forceinline__ h2 mkh2(float a, float b) {
    h2 r; r.x = (_Float16)a; r.y = (_Float16)b; return r;
}

__device__ __forceinline__ float rcp_fast(float x) {
    return __builtin_amdgcn_rcpf(x);
}

__device__ __forceinline__ float tanh_fast(float x) {
    return fmaf(rcp_fast(1.0f + __expf(-2.0f * x)), 2.0f, -1.0f);
}

__device__ __forceinline__ float sigmoid_fast(float x) {
    return rcp_fast(1.0f + __expf(-x));
}

// One workgroup per batch element; 512 threads (8 waves), grid = 128 blocks.
//
// The per-step [512x192]*[192x1] fp16 matvec runs on the MATRIX pipe:
// wave w owns 4 MFMA M-tiles (one per gate g) covering j in [16w,16w+16).
// A-fragments = weight rows, resident in VGPRs (24 tiles x 4 VGPR = 96).
// B = the [x|h] step vector broadcast to all 16 columns (every lane loads
// real data; all 16 output columns are identical valid copies).
// Layouts (16x16x32_f16): A: row=lane&15, k=8*(lane>>4)+i.
//                         B: col=lane&15, k=8*(lane>>4)+i.
//                         C/D: col=lane&15, row=4*(lane>>4)+reg (m89).
// After MFMA, lane (grp=lane>>4, r=lane&3) selects accumulator element r ->
// it owns h-element j = 16w + 4*grp + r (4-way redundant across columns).
// Activations thus cost 1 j per lane, same as the fdot2 kernel, but the
// 96-fdot2 dot work is gone from the VALU.
__global__ __launch_bounds__(512, 2) void lstm_fused_kernel(
    const float* __restrict__ input,  // [B,T,I]
    const float* __restrict__ h0,     // [B,H]
    const float* __restrict__ c0,     // [B,H]
    const float* __restrict__ W_ih,   // [4H,I]
    const float* __restrict__ W_hh,   // [4H,H]
    const float* __restrict__ b_ih,   // [4H]
    const float* __restrict__ b_hh,   // [4H]
    float* __restrict__ out)          // [B*H] h_last, then [B,T,H] encoded
{
    // [buf][h2 idx]: idx [0,32) = x_t (64 halfs), [32,96) = h (128 halfs).
    __shared__ __align__(16) h2 s_xh[2][KK / 2];

    const int tid  = threadIdx.x;
    const int b    = blockIdx.x;
    const int lane = tid & 63;
    const int w    = tid >> 6;          // wave 0..7
    const int grp  = lane >> 4;         // 0..3  (k-group / D-row-group)
    const int m    = lane & 15;         // A row within tile / D col
    const int r    = lane & 3;          // selected accumulator element
    const int jb   = (w << 4) | (grp << 2);   // j base for this lane's rows
    const int jown = jb | r;                  // h element this lane owns

    // ---- A-fragments: weight rows fp32 -> fp16, MFMA layout ----
    // tile (g, kt): A[row = g*128 + 16w + m][k = 32*kt + 8*grp + i], i=0..7
    f16x8 wf[4][6];   // 96 VGPRs
#pragma unroll
    for (int g = 0; g < 4; ++g) {
        const int row = (g << 7) | (w << 4) | m;
#pragma unroll
        for (int kt = 0; kt < 6; ++kt) {
            const int k0 = 32 * kt + 8 * grp;   // [0,184], never straddles II
            const float* src = (k0 < II) ? (W_ih + row * II + k0)
                                         : (W_hh + row * HH + (k0 - II));
            const float4 v0 = reinterpret_cast<const float4*>(src)[0];
            const float4 v1 = reinterpret_cast<const float4*>(src)[1];
            f16x8 f;
            f[0] = (_Float16)v0.x; f[1] = (_Float16)v0.y;
            f[2] = (_Float16)v0.z; f[3] = (_Float16)v0.w;
            f[4] = (_Float16)v1.x; f[5] = (_Float16)v1.y;
            f[6] = (_Float16)v1.z; f[7] = (_Float16)v1.w;
            wf[g][kt] = f;
        }
    }

    // ---- bias fragments (accumulator C-init; free bias add) ----
    // biasf[g][rr] = bias of row g*128 + jb + rr  (D rows of this lane)
    f32x4 biasf[4];
#pragma unroll
    for (int g = 0; g < 4; ++g) {
#pragma unroll
        for (int rr = 0; rr < 4; ++rr) {
            const int row = (g << 7) | (jb + rr);
            biasf[g][rr] = b_ih[row] + b_hh[row];
        }
    }

    // ---- state init ----
    float c = c0[(size_t)b * HH + jown];   // redundant across 4 column-copies
    if (tid < 64) {
        float2 hv = reinterpret_cast<const float2*>(h0 + (size_t)b * HH)[tid];
        s_xh[0][32 + tid] = mkh2(hv.x, hv.y);
    }

    // ---- x prefetch ring: threads 0..31 hold 4 future float2 of x ----
    const float2* xin = reinterpret_cast<const float2*>(input) + (size_t)b * TT * 32 + tid;
    float2 xb0, xb1, xb2, xb3;
    if (tid < 32) {
        xb0 = xin[(size_t)0 * 32];
        xb1 = xin[(size_t)1 * 32];
        xb2 = xin[(size_t)2 * 32];
        xb3 = xin[(size_t)3 * 32];
        s_xh[0][tid] = mkh2(xb0.x, xb0.y);   // stage x for step 0
        xb0 = xin[(size_t)4 * 32];           // xb0 now holds x_4
    }
    __syncthreads();

    float* out_h = out;            // [B*H]
    float* out_e = out + BB * HH;  // [B*T*H]
    float hlast = 0.0f;
    const bool writer = (lane & 12) == 0;    // col == r: one lane per j

    auto step = [&](int t, float2& xbn) {
        const int cb = t & 1, nb = cb ^ 1;

        if (tid < 32) {
            s_xh[nb][tid] = mkh2(xbn.x, xbn.y);
            int tn = t + 5; if (tn > TT - 1) tn = TT - 1;   // clamped, harmless
            xbn = xin[(size_t)tn * 32];
        }

        // B-fragments: halfs k = 32*kt + 8*grp .. +8 of [x|h]  (16B, broadcast
        // across the 16 lanes of each k-group -> conflict-free)
        const char* base = reinterpret_cast<const char*>(s_xh[cb]) + 16 * grp;
        f16x8 bf[6];
#pragma unroll
        for (int kt = 0; kt < 6; ++kt)
            bf[kt] = __builtin_bit_cast(f16x8,
                *reinterpret_cast<const uint4*>(base + 64 * kt));

        // 4 independent 6-deep MFMA chains (one per gate), C seeded with bias.
        f32x4 acc0 = biasf[0], acc1 = biasf[1], acc2 = biasf[2], acc3 = biasf[3];
#pragma unroll
        for (int kt = 0; kt < 6; ++kt) {
            acc0 = __builtin_amdgcn_mfma_f32_16x16x32_f16(wf[0][kt], bf[kt], acc0, 0, 0, 0);
            acc1 = __builtin_amdgcn_mfma_f32_16x16x32_f16(wf[1][kt], bf[kt], acc1, 0, 0, 0);
            acc2 = __builtin_amdgcn_mfma_f32_16x16x32_f16(wf[2][kt], bf[kt], acc2, 0, 0, 0);
            acc3 = __builtin_amdgcn_mfma_f32_16x16x32_f16(wf[3][kt], bf[kt], acc3, 0, 0, 0);
        }

        // select accumulator element r (2 cndmasks per gate; static indices)
        const bool s1 = (lane & 1) != 0, s2 = (lane & 2) != 0;
        float p0 = s2 ? (s1 ? acc0[3] : acc0[2]) : (s1 ? acc0[1] : acc0[0]);
        float p1 = s2 ? (s1 ? acc1[3] : acc1[2]) : (s1 ? acc1[1] : acc1[0]);
        float p2 = s2 ? (s1 ? acc2[3] : acc2[2]) : (s1 ? acc2[1] : acc2[0]);
        float p3 = s2 ? (s1 ? acc3[3] : acc3[2]) : (s1 ? acc3[1] : acc3[0]);

        float ig = sigmoid_fast(p0);
        float fg = sigmoid_fast(p1);
        float gg = tanh_fast(p2);
        float og = sigmoid_fast(p3);

        c = fmaf(fg, c, ig * gg);
        float hv = og * tanh_fast(c);
        hlast = hv;

        if (writer) {
            reinterpret_cast<_Float16*>(s_xh[nb])[II + jown] = (_Float16)hv;
            out_e[((size_t)b * TT + t) * HH + jown] = hv;
        }

        __syncthreads();
    };

    for (int t0 = 0; t0 < TT; t0 += 4) {
        step(t0 + 0, xb1);
        step(t0 + 1, xb2);
        step(t0 + 2, xb3);
        step(t0 + 3, xb0);
    }

    if (writer) out_h[(size_t)b * HH + jown] = hlast;
}

extern "C" void kernel_launch(void* const* d_in, const int* in_sizes, int n_in,
                              void* d_out, int out_size, void* d_ws, size_t ws_size,
                              hipStream_t stream) {
    const float* input = (const float*)d_in[0];
    const float* h0    = (const float*)d_in[1];
    const float* c0    = (const float*)d_in[2];
    const float* W_ih  = (const float*)d_in[3];
    const float* W_hh  = (const float*)d_in[4];
    const float* b_ih  = (const float*)d_in[5];
    const float* b_hh  = (const float*)d_in[6];
    float* out = (float*)d_out;

    hipLaunchKernelGGL(lstm_fused_kernel, dim3(BB), dim3(512), 0, stream,
                       input, h0, c0, W_ih, W_hh, b_ih, b_hh, out);
}